// Round 15
// baseline (300.477 us; speedup 1.0000x reference)
//
#include <hip/hip_runtime.h>
#include <hip/hip_bf16.h>

#define TT 8192
#define DD 2048
#define OO 2048
#define EE 8

typedef __attribute__((ext_vector_type(4))) float f32x4;
typedef __attribute__((ext_vector_type(8))) short s16x8;
typedef __attribute__((ext_vector_type(4))) short s16x4;

// round-to-nearest-even fp32 -> bf16 bits
__device__ __forceinline__ short f2bf(float f) {
    union { float f; unsigned u; } v; v.f = f;
    unsigned r = (v.u + 0x7FFFu + ((v.u >> 16) & 1u)) >> 16;
    return (short)(unsigned short)r;
}
__device__ __forceinline__ float bf2f(short s) {
    union { unsigned u; float f; } v; v.u = ((unsigned)(unsigned short)s) << 16;
    return v.f;
}

// converts ew (n8w groups of 8) then x (n8x groups) in one grid-strided launch
__global__ __launch_bounds__(256) void cvt_both_kernel(
    const float* __restrict__ ew, short* __restrict__ wbf, long n8w,
    const float* __restrict__ x, short* __restrict__ xbf, long n8x)
{
    long i = (long)blockIdx.x * blockDim.x + threadIdx.x;
    long stride = (long)gridDim.x * blockDim.x;
    long total = n8w + n8x;
    for (; i < total; i += stride) {
        const float* in; short* out; long k;
        if (i < n8w) { in = ew; out = wbf; k = i; }
        else         { in = x;  out = xbf; k = i - n8w; }
        f32x4 a = ((const f32x4*)in)[k * 2];
        f32x4 b = ((const f32x4*)in)[k * 2 + 1];
        s16x8 r;
        r[0] = f2bf(a[0]); r[1] = f2bf(a[1]); r[2] = f2bf(a[2]); r[3] = f2bf(a[3]);
        r[4] = f2bf(b[0]); r[5] = f2bf(b[1]); r[6] = f2bf(b[2]); r[7] = f2bf(b[3]);
        ((s16x8*)out)[k] = r;
    }
}

// one wave per token: logits = tanh(x @ w1^T) @ w2^T, top-2, softmax.
__global__ __launch_bounds__(256) void gate_kernel(
    const float* __restrict__ x, const float* __restrict__ w1, const float* __restrict__ w2,
    int* __restrict__ tk_idx, float* __restrict__ tk_score)
{
    const int lane = threadIdx.x & 63;
    const int wid = threadIdx.x >> 6;
    const int t = blockIdx.x * 4 + wid;
    const float* xt = x + (long)t * DD;

    float acc[8] = {0.f,0.f,0.f,0.f,0.f,0.f,0.f,0.f};
#pragma unroll
    for (int i = 0; i < DD / 256; ++i) {
        f32x4 xv = *(const f32x4*)&xt[i * 256 + lane * 4];
#pragma unroll
        for (int e2 = 0; e2 < 8; ++e2) {
            f32x4 wv = *(const f32x4*)&w1[e2 * DD + i * 256 + lane * 4];
            acc[e2] += xv[0]*wv[0] + xv[1]*wv[1] + xv[2]*wv[2] + xv[3]*wv[3];
        }
    }
#pragma unroll
    for (int e2 = 0; e2 < 8; ++e2) {
#pragma unroll
        for (int off = 32; off > 0; off >>= 1)
            acc[e2] += __shfl_xor(acc[e2], off, 64);
    }

    float th[8], lg[8];
#pragma unroll
    for (int e2 = 0; e2 < 8; ++e2) th[e2] = tanhf(acc[e2]);
#pragma unroll
    for (int eo = 0; eo < 8; ++eo) {
        float s = 0.f;
#pragma unroll
        for (int e2 = 0; e2 < 8; ++e2) s += th[e2] * w2[eo * 8 + e2];
        lg[eo] = s;
    }
    int e0 = 0;
#pragma unroll
    for (int q = 1; q < 8; ++q) if (lg[q] > lg[e0]) e0 = q;
    int e1 = (e0 == 0) ? 1 : 0;
#pragma unroll
    for (int q = 0; q < 8; ++q) if (q != e0 && lg[q] > lg[e1]) e1 = q;

    float d = expf(lg[e1] - lg[e0]);
    float s0 = 1.f / (1.f + d);
    float s1 = d / (1.f + d);

    if (lane == 0) {
        tk_idx[t * 2] = e0; tk_idx[t * 2 + 1] = e1;
        tk_score[t * 2] = s0; tk_score[t * 2 + 1] = s1;
    }
}

// one block per expert: deterministic token-order compaction via ballot prefix scan.
// List entry = t*2 + slot (slot: 0 = first choice, 1 = second).
__global__ __launch_bounds__(256) void build_lists(
    const int* __restrict__ tk_idx, const float* __restrict__ tk_score,
    int* __restrict__ tok_list, float* __restrict__ score_list, int* __restrict__ cnt,
    float* __restrict__ imp)
{
    const int e = blockIdx.x;
    const int lane = threadIdx.x & 63;
    const int wid = threadIdx.x >> 6;
    __shared__ int wsum[4];
    __shared__ float wsumF[4];
    int base = 0;
    float ssum = 0.f;
    for (int t0 = 0; t0 < TT; t0 += 256) {
        int t = t0 + threadIdx.x;
        int i0 = tk_idx[t * 2], i1 = tk_idx[t * 2 + 1];
        bool has = (i0 == e) || (i1 == e);
        int slot = (i0 == e) ? 0 : 1;
        float sc = (i0 == e) ? tk_score[t * 2] : tk_score[t * 2 + 1];
        unsigned long long m = __ballot(has);
        int prefix = __popcll(m & ((1ull << lane) - 1ull));
        if (lane == 0) wsum[wid] = __popcll(m);
        __syncthreads();
        int woff = 0;
#pragma unroll
        for (int w = 0; w < 4; ++w) woff += (w < wid) ? wsum[w] : 0;
        int total = wsum[0] + wsum[1] + wsum[2] + wsum[3];
        if (has) {
            int p = base + woff + prefix;
            tok_list[e * TT + p] = t * 2 + slot;
            score_list[e * TT + p] = sc;
            ssum += sc;
        }
        base += total;
        __syncthreads();
    }
#pragma unroll
    for (int off = 32; off > 0; off >>= 1)
        ssum += __shfl_xor(ssum, off, 64);
    if (lane == 0) wsumF[wid] = ssum;
    __syncthreads();
    if (threadIdx.x == 0) {
        cnt[e] = base;
        imp[e] = wsumF[0] + wsumF[1] + wsumF[2] + wsumF[3];
    }
}

// y[t][o] = float(part0) + float(part1); block 0 thread 0 also writes the
// cv^2 balance loss (cnt/imp were finalized two kernels ago).
__global__ __launch_bounds__(256) void combine_kernel(float* __restrict__ y,
                                                      const short* __restrict__ part0,
                                                      const short* __restrict__ part1,
                                                      const float* __restrict__ imp,
                                                      const int* __restrict__ cnt) {
    if (blockIdx.x == 0 && threadIdx.x == 0) {
        float im[8], ld[8];
        float mi = 0.f, ml = 0.f;
#pragma unroll
        for (int q = 0; q < 8; ++q) {
            im[q] = imp[q]; ld[q] = (float)cnt[q];
            mi += im[q]; ml += ld[q];
        }
        mi *= 0.125f; ml *= 0.125f;
        float vi = 0.f, vl = 0.f;
#pragma unroll
        for (int q = 0; q < 8; ++q) {
            float a = im[q] - mi; vi += a * a;
            float b = ld[q] - ml; vl += b * b;
        }
        vi /= 7.f; vl /= 7.f;
        y[(size_t)TT * OO] = 0.01f * (vi / (mi * mi + 1e-10f) + vl / (ml * ml + 1e-10f));
    }
    long i = (long)blockIdx.x * blockDim.x + threadIdx.x;
    long stride = (long)gridDim.x * blockDim.x;
    const long n4 = (long)TT * OO / 4;
    for (; i < n4; i += stride) {
        s16x4 p0 = ((const s16x4*)part0)[i];
        s16x4 p1 = ((const s16x4*)part1)[i];
        f32x4 v;
        v[0] = bf2f(p0[0]) + bf2f(p1[0]);
        v[1] = bf2f(p0[1]) + bf2f(p1[1]);
        v[2] = bf2f(p0[2]) + bf2f(p1[2]);
        v[3] = bf2f(p0[3]) + bf2f(p1[3]);
        ((f32x4*)y)[i] = v;
    }
}

#define GLD16(gsrc, ldst) \
    __builtin_amdgcn_global_load_lds((const __attribute__((address_space(1))) unsigned int*)(gsrc), \
                                     (__attribute__((address_space(3))) unsigned int*)(ldst), 16, 0, 0)

#define BAR() __builtin_amdgcn_s_barrier()

// Grouped GEMM, round-15: 3-deep A / 2-deep B pipeline in EXACTLY 160 KiB LDS
// (stok/ssc moved to direct global reads: tok_list/score_list are L2-hot and
// wave-broadcast-friendly).
// Layout: Abuf[k] at k*32768 (k=0..2), Bbuf[k] at 98304 + k*32768 (k=0..1).
// kt j: reads Abuf[j%3], Bbuf[j&1]; stages B(j+1)->Bbuf[(j+1)&1] then
// A(j+2)->Abuf[(j+2)%3] (both buffers last read in kt j-1, behind that kt's
// lgkmcnt(0)+barrier -> write-safe).
// Gate at kt end: vmcnt(4) -- outstanding (old->new) = A(j+1)[4], B(j+1)[4],
// A(j+2)[4]; waits the 8 oldest, leaves A(j+2) in flight. A(j+1) was issued a
// FULL kt earlier (vs same-kt in r14), B(j+1) ~2500 MFMA-covered cycles ago.
// Never drains to 0 in the main loop. One barrier per kt.
__global__ __launch_bounds__(512, 2) void moe_gemm(
    const short* __restrict__ xbf, const short* __restrict__ wbf,
    const float* __restrict__ eb,
    const int* __restrict__ tok_list, const float* __restrict__ score_list,
    const int* __restrict__ cnt, short* __restrict__ part0, short* __restrict__ part1)
{
    const int e = blockIdx.z;
    const int n_e = cnt[e];
    const int xb = blockIdx.x, yb = blockIdx.y;
    const int cb = ((xb >> 2) << 2) + (yb & 3);
    const int rb = (xb & 3) + ((yb >> 2) << 2);
    const int row0 = rb * 256;
    if (row0 >= n_e) return;
    const int col0 = cb * 256;

    __shared__ alignas(16) short lds[81920];   // 160 KiB exactly: 3xA(32K) + 2xB(32K)

    const int tid = threadIdx.x;
    const int lane = tid & 63;
    const int wid = tid >> 6;                 // 0..7
    const int wr = wid >> 2, wc = wid & 3;    // 2M x 4N
    const int fr = lane & 15, fq = lane >> 4;
    const char* ldsb = (const char*)lds;

    const int r_ = tid >> 3;                               // 0..63
    const int csw = ((tid & 7) ^ (r_ & 7)) * 8;            // swizzled element offset
    const short* aS[4];
#pragma unroll
    for (int g = 0; g < 4; ++g) {
        int sl = row0 + g * 64 + r_;
        if (sl >= n_e) sl = n_e - 1;          // pad rows clamp (stores predicated off)
        aS[g] = xbf + (long)(tok_list[e * TT + sl] >> 1) * DD + csw;
    }
    const short* bS[4];
#pragma unroll
    for (int g = 0; g < 4; ++g)
        bS[g] = wbf + (long)e * OO * DD + (long)(col0 + g * 64 + r_) * DD + csw;

#define STAGE_A(g, kt) GLD16(aS[g] + (kt) * 64, (char*)lds + ((kt) % 3) * 32768 + ((g) * 512 + tid) * 16)
#define STAGE_B(g, kt) GLD16(bS[g] + (kt) * 64, (char*)lds + 98304 + ((kt) & 1) * 32768 + ((g) * 512 + tid) * 16)

    const int aBase = (wr * 128 + fr) * 128;               // within A buf
    const int bBase = (wc * 64 + fr) * 128;                // within B buf
    const int sw0 = (fq ^ (fr & 7)) * 16;
    const int sw1 = ((fq + 4) ^ (fr & 7)) * 16;

    f32x4 acc[8][4];
#pragma unroll
    for (int m = 0; m < 8; ++m)
#pragma unroll
        for (int n = 0; n < 4; ++n) acc[m][n] = f32x4{0.f, 0.f, 0.f, 0.f};

    // prologue: A(0)->Abuf0, B(0)->Bbuf0, A(1)->Abuf1 (issued LAST so vmcnt(4)
    // leaves exactly A(1) in flight; A(0),B(0) forced landed).
    STAGE_A(0, 0); STAGE_A(1, 0); STAGE_A(2, 0); STAGE_A(3, 0);
    STAGE_B(0, 0); STAGE_B(1, 0); STAGE_B(2, 0); STAGE_B(3, 0);
    STAGE_A(0, 1); STAGE_A(1, 1); STAGE_A(2, 1); STAGE_A(3, 1);
    asm volatile("s_waitcnt vmcnt(4)");
    BAR();

    int fA = 0;                               // j % 3
#pragma unroll 1
    for (int j = 0; j < DD / 64; ++j) {
        const int fbA = fA * 32768;
        const int fbB = 98304 + (j & 1) * 32768;
        int fA2 = fA + 2; if (fA2 >= 3) fA2 -= 3;     // (j+2) % 3
        const int fbA2 = fA2 * 32768;
        const bool st1 = (j + 1) < DD / 64;
        const bool st2 = (j + 2) < DD / 64;

        s16x8 a0[4][2], a1[4][2], bb[4][2];

        // reads: A[mh0] (8) + all B (8)
#pragma unroll
        for (int mm = 0; mm < 4; ++mm) {
            a0[mm][0] = *(const s16x8*)(ldsb + fbA + aBase + mm * 2048 + sw0);
            a0[mm][1] = *(const s16x8*)(ldsb + fbA + aBase + mm * 2048 + sw1);
        }
#pragma unroll
        for (int n = 0; n < 4; ++n) {
            bb[n][0] = *(const s16x8*)(ldsb + fbB + bBase + n * 2048 + sw0);
            bb[n][1] = *(const s16x8*)(ldsb + fbB + bBase + n * 2048 + sw1);
        }
        // stage B(j+1) first (it's gated this kt), then A(j+2) (stays in flight)
        if (st1) {
            STAGE_B(0, j + 1); STAGE_B(1, j + 1);
            STAGE_B(2, j + 1); STAGE_B(3, j + 1);
        }
        if (st2) {
            GLD16(aS[0] + (j + 2) * 64, (char*)lds + fbA2 + (0 * 512 + tid) * 16);
            GLD16(aS[1] + (j + 2) * 64, (char*)lds + fbA2 + (1 * 512 + tid) * 16);
            GLD16(aS[2] + (j + 2) * 64, (char*)lds + fbA2 + (2 * 512 + tid) * 16);
            GLD16(aS[3] + (j + 2) * 64, (char*)lds + fbA2 + (3 * 512 + tid) * 16);
        }
        // MFMA half 1
        __builtin_amdgcn_s_setprio(1);
#pragma unroll
        for (int mm = 0; mm < 4; ++mm)
#pragma unroll
            for (int n = 0; n < 4; ++n) {
                acc[mm][n] = __builtin_amdgcn_mfma_f32_16x16x32_bf16(a0[mm][0], bb[n][0], acc[mm][n], 0, 0, 0);
                acc[mm][n] = __builtin_amdgcn_mfma_f32_16x16x32_bf16(a0[mm][1], bb[n][1], acc[mm][n], 0, 0, 0);
            }
        __builtin_amdgcn_s_setprio(0);
        // reads: A[mh1] (8), then MFMA half 2
#pragma unroll
        for (int mm = 0; mm < 4; ++mm) {
            a1[mm][0] = *(const s16x8*)(ldsb + fbA + aBase + 8192 + mm * 2048 + sw0);
            a1[mm][1] = *(const s16x8*)(ldsb + fbA + aBase + 8192 + mm * 2048 + sw1);
        }
        __builtin_amdgcn_s_setprio(1);
#pragma unroll
        for (int mm = 0; mm < 4; ++mm)
#pragma unroll
            for (int n = 0; n < 4; ++n) {
                acc[4 + mm][n] = __builtin_amdgcn_mfma_f32_16x16x32_bf16(a1[mm][0], bb[n][0], acc[4 + mm][n], 0, 0, 0);
                acc[4 + mm][n] = __builtin_amdgcn_mfma_f32_16x16x32_bf16(a1[mm][1], bb[n][1], acc[4 + mm][n], 0, 0, 0);
            }
        __builtin_amdgcn_s_setprio(0);

        // end-of-kt: P-reads retired; A(j+1)+B(j+1) landed; A(j+2) may fly.
        asm volatile("s_waitcnt lgkmcnt(0)");
        __builtin_amdgcn_sched_barrier(0);
        if (st2) { asm volatile("s_waitcnt vmcnt(4)"); }
        else     { asm volatile("s_waitcnt vmcnt(0)"); }
        __builtin_amdgcn_sched_barrier(0);
        BAR();
        fA = (fA == 2) ? 0 : fA + 1;
    }

    // ---- epilogue: bias + score; slot-0 -> part0, slot-1 -> part1 (both bf16)
    float bval[4];
#pragma unroll
    for (int n = 0; n < 4; ++n)
        bval[n] = eb[e * OO + col0 + wc * 64 + n * 16 + fr];

    // C/D layout: col = lane&15, row = (lane>>4)*4 + jj  [m89/m91-verified]
#pragma unroll
    for (int m = 0; m < 8; ++m) {
#pragma unroll
        for (int jj = 0; jj < 4; ++jj) {
            int tslot = wr * 128 + m * 16 + fq * 4 + jj;
            if (row0 + tslot < n_e) {
                int packed = tok_list[e * TT + row0 + tslot];   // L2-hot, wave-broadcast
                float s = score_list[e * TT + row0 + tslot];
                int t = packed >> 1;
                short* dst = ((packed & 1) == 0) ? part0 : part1;
#pragma unroll
                for (int n = 0; n < 4; ++n) {
                    int o = col0 + wc * 64 + n * 16 + fr;
                    dst[(long)t * OO + o] = f2bf(s * (acc[m][n][jj] + bval[n]));
                }
            }
        }
    }
#undef STAGE_A
#undef STAGE_B
}

extern "C" void kernel_launch(void* const* d_in, const int* in_sizes, int n_in,
                              void* d_out, int out_size, void* d_ws, size_t ws_size,
                              hipStream_t stream) {
    const float* x  = (const float*)d_in[0];
    const float* w1 = (const float*)d_in[1];
    const float* w2 = (const float*)d_in[2];
    const float* ew = (const float*)d_in[3];
    const float* eb = (const float*)d_in[4];
    float* y = (float*)d_out;   // [T*O] then gate_loss at [T*O]

    char* ws = (char*)d_ws;
    short* xbf = (short*)ws;            ws += (size_t)TT * DD * 2;
    short* wbf = (short*)ws;            ws += (size_t)EE * OO * DD * 2;
    short* part0 = (short*)ws;          ws += (size_t)TT * OO * 2;
    short* part1 = (short*)ws;          ws += (size_t)TT * OO * 2;
    int*   tok_list = (int*)ws;         ws += (size_t)EE * TT * 4;
    float* score_list = (float*)ws;     ws += (size_t)EE * TT * 4;
    int*   tk_idx = (int*)ws;           ws += (size_t)TT * 2 * 4;
    float* tk_score = (float*)ws;       ws += (size_t)TT * 2 * 4;
    int*   cnt = (int*)ws;              ws += 64;
    float* imp = (float*)ws;            ws += 64;

    cvt_both_kernel<<<8192, 256, 0, stream>>>(ew, wbf, (long)EE * OO * DD / 8,
                                              x, xbf, (long)TT * DD / 8);
    gate_kernel<<<TT / 4, 256, 0, stream>>>(x, w1, w2, tk_idx, tk_score);
    build_lists<<<EE, 256, 0, stream>>>(tk_idx, tk_score, tok_list, score_list, cnt, imp);
    moe_gemm<<<dim3(8, 32, EE), 512, 0, stream>>>(
        xbf, wbf, eb, tok_list, score_list, cnt, part0, part1);
    combine_kernel<<<2048, 256, 0, stream>>>(y, part0, part1, imp, cnt);
}

// Round 16
// 285.714 us; speedup vs baseline: 1.0517x; 1.0517x over previous
//
#include <hip/hip_runtime.h>
#include <hip/hip_bf16.h>

#define TT 8192
#define DD 2048
#define OO 2048
#define EE 8

typedef __attribute__((ext_vector_type(4))) float f32x4;
typedef __attribute__((ext_vector_type(8))) short s16x8;
typedef __attribute__((ext_vector_type(4))) short s16x4;

// round-to-nearest-even fp32 -> bf16 bits
__device__ __forceinline__ short f2bf(float f) {
    union { float f; unsigned u; } v; v.f = f;
    unsigned r = (v.u + 0x7FFFu + ((v.u >> 16) & 1u)) >> 16;
    return (short)(unsigned short)r;
}
__device__ __forceinline__ float bf2f(short s) {
    union { unsigned u; float f; } v; v.u = ((unsigned)(unsigned short)s) << 16;
    return v.f;
}

// converts ew (n8w groups of 8) then x (n8x groups) in one grid-strided launch
__global__ __launch_bounds__(256) void cvt_both_kernel(
    const float* __restrict__ ew, short* __restrict__ wbf, long n8w,
    const float* __restrict__ x, short* __restrict__ xbf, long n8x)
{
    long i = (long)blockIdx.x * blockDim.x + threadIdx.x;
    long stride = (long)gridDim.x * blockDim.x;
    long total = n8w + n8x;
    for (; i < total; i += stride) {
        const float* in; short* out; long k;
        if (i < n8w) { in = ew; out = wbf; k = i; }
        else         { in = x;  out = xbf; k = i - n8w; }
        f32x4 a = ((const f32x4*)in)[k * 2];
        f32x4 b = ((const f32x4*)in)[k * 2 + 1];
        s16x8 r;
        r[0] = f2bf(a[0]); r[1] = f2bf(a[1]); r[2] = f2bf(a[2]); r[3] = f2bf(a[3]);
        r[4] = f2bf(b[0]); r[5] = f2bf(b[1]); r[6] = f2bf(b[2]); r[7] = f2bf(b[3]);
        ((s16x8*)out)[k] = r;
    }
}

// one wave per token: logits = tanh(x @ w1^T) @ w2^T, top-2, softmax.
__global__ __launch_bounds__(256) void gate_kernel(
    const float* __restrict__ x, const float* __restrict__ w1, const float* __restrict__ w2,
    int* __restrict__ tk_idx, float* __restrict__ tk_score)
{
    const int lane = threadIdx.x & 63;
    const int wid = threadIdx.x >> 6;
    const int t = blockIdx.x * 4 + wid;
    const float* xt = x + (long)t * DD;

    float acc[8] = {0.f,0.f,0.f,0.f,0.f,0.f,0.f,0.f};
#pragma unroll
    for (int i = 0; i < DD / 256; ++i) {
        f32x4 xv = *(const f32x4*)&xt[i * 256 + lane * 4];
#pragma unroll
        for (int e2 = 0; e2 < 8; ++e2) {
            f32x4 wv = *(const f32x4*)&w1[e2 * DD + i * 256 + lane * 4];
            acc[e2] += xv[0]*wv[0] + xv[1]*wv[1] + xv[2]*wv[2] + xv[3]*wv[3];
        }
    }
#pragma unroll
    for (int e2 = 0; e2 < 8; ++e2) {
#pragma unroll
        for (int off = 32; off > 0; off >>= 1)
            acc[e2] += __shfl_xor(acc[e2], off, 64);
    }

    float th[8], lg[8];
#pragma unroll
    for (int e2 = 0; e2 < 8; ++e2) th[e2] = tanhf(acc[e2]);
#pragma unroll
    for (int eo = 0; eo < 8; ++eo) {
        float s = 0.f;
#pragma unroll
        for (int e2 = 0; e2 < 8; ++e2) s += th[e2] * w2[eo * 8 + e2];
        lg[eo] = s;
    }
    int e0 = 0;
#pragma unroll
    for (int q = 1; q < 8; ++q) if (lg[q] > lg[e0]) e0 = q;
    int e1 = (e0 == 0) ? 1 : 0;
#pragma unroll
    for (int q = 0; q < 8; ++q) if (q != e0 && lg[q] > lg[e1]) e1 = q;

    float d = expf(lg[e1] - lg[e0]);
    float s0 = 1.f / (1.f + d);
    float s1 = d / (1.f + d);

    if (lane == 0) {
        tk_idx[t * 2] = e0; tk_idx[t * 2 + 1] = e1;
        tk_score[t * 2] = s0; tk_score[t * 2 + 1] = s1;
    }
}

// one block per expert: deterministic token-order compaction via ballot prefix scan.
// List entry = t*2 + slot (slot: 0 = first choice, 1 = second).
__global__ __launch_bounds__(256) void build_lists(
    const int* __restrict__ tk_idx, const float* __restrict__ tk_score,
    int* __restrict__ tok_list, float* __restrict__ score_list, int* __restrict__ cnt,
    float* __restrict__ imp)
{
    const int e = blockIdx.x;
    const int lane = threadIdx.x & 63;
    const int wid = threadIdx.x >> 6;
    __shared__ int wsum[4];
    __shared__ float wsumF[4];
    int base = 0;
    float ssum = 0.f;
    for (int t0 = 0; t0 < TT; t0 += 256) {
        int t = t0 + threadIdx.x;
        int i0 = tk_idx[t * 2], i1 = tk_idx[t * 2 + 1];
        bool has = (i0 == e) || (i1 == e);
        int slot = (i0 == e) ? 0 : 1;
        float sc = (i0 == e) ? tk_score[t * 2] : tk_score[t * 2 + 1];
        unsigned long long m = __ballot(has);
        int prefix = __popcll(m & ((1ull << lane) - 1ull));
        if (lane == 0) wsum[wid] = __popcll(m);
        __syncthreads();
        int woff = 0;
#pragma unroll
        for (int w = 0; w < 4; ++w) woff += (w < wid) ? wsum[w] : 0;
        int total = wsum[0] + wsum[1] + wsum[2] + wsum[3];
        if (has) {
            int p = base + woff + prefix;
            tok_list[e * TT + p] = t * 2 + slot;
            score_list[e * TT + p] = sc;
            ssum += sc;
        }
        base += total;
        __syncthreads();
    }
#pragma unroll
    for (int off = 32; off > 0; off >>= 1)
        ssum += __shfl_xor(ssum, off, 64);
    if (lane == 0) wsumF[wid] = ssum;
    __syncthreads();
    if (threadIdx.x == 0) {
        cnt[e] = base;
        imp[e] = wsumF[0] + wsumF[1] + wsumF[2] + wsumF[3];
    }
}

// y[t][o] = float(part0) + float(part1); block 0 thread 0 also writes the
// cv^2 balance loss (cnt/imp were finalized two kernels ago).
__global__ __launch_bounds__(256) void combine_kernel(float* __restrict__ y,
                                                      const short* __restrict__ part0,
                                                      const short* __restrict__ part1,
                                                      const float* __restrict__ imp,
                                                      const int* __restrict__ cnt) {
    if (blockIdx.x == 0 && threadIdx.x == 0) {
        float im[8], ld[8];
        float mi = 0.f, ml = 0.f;
#pragma unroll
        for (int q = 0; q < 8; ++q) {
            im[q] = imp[q]; ld[q] = (float)cnt[q];
            mi += im[q]; ml += ld[q];
        }
        mi *= 0.125f; ml *= 0.125f;
        float vi = 0.f, vl = 0.f;
#pragma unroll
        for (int q = 0; q < 8; ++q) {
            float a = im[q] - mi; vi += a * a;
            float b = ld[q] - ml; vl += b * b;
        }
        vi /= 7.f; vl /= 7.f;
        y[(size_t)TT * OO] = 0.01f * (vi / (mi * mi + 1e-10f) + vl / (ml * ml + 1e-10f));
    }
    long i = (long)blockIdx.x * blockDim.x + threadIdx.x;
    long stride = (long)gridDim.x * blockDim.x;
    const long n4 = (long)TT * OO / 4;
    for (; i < n4; i += stride) {
        s16x4 p0 = ((const s16x4*)part0)[i];
        s16x4 p1 = ((const s16x4*)part1)[i];
        f32x4 v;
        v[0] = bf2f(p0[0]) + bf2f(p1[0]);
        v[1] = bf2f(p0[1]) + bf2f(p1[1]);
        v[2] = bf2f(p0[2]) + bf2f(p1[2]);
        v[3] = bf2f(p0[3]) + bf2f(p1[3]);
        ((f32x4*)y)[i] = v;
    }
}

#define GLD16(gsrc, ldst) \
    __builtin_amdgcn_global_load_lds((const __attribute__((address_space(1))) unsigned int*)(gsrc), \
                                     (__attribute__((address_space(3))) unsigned int*)(ldst), 16, 0, 0)

#define BAR() __builtin_amdgcn_s_barrier()

// Grouped GEMM (r14 config -- session best, 178 us / MfmaUtil 34.5):
// ONE barrier per kt. Loop body: reads(24) of buf P -> stage ALL 8 half-tiles
// of kt j+1 into buf Q (Q hazard-free: last read in kt j-1, behind a barrier)
// -> MFMA(64) -> lgkmcnt(0)+sched_barrier (pin P-reads retired; rule-18 fence)
// -> vmcnt(0) (Q landed; issued ~2500 cyc earlier, covered by the MFMA block)
// -> BAR. Epilogue: bf16 part0/part1 slot-split, no atomics. 2-D XCD placement
// (XCD=(cb>>2)*4+(rb&3): A-panel col-sharers on 2 XCDs, B-panel row-sharers
// on 4; FETCH 262->~205 MB).
__global__ __launch_bounds__(512, 2) void moe_gemm(
    const short* __restrict__ xbf, const short* __restrict__ wbf,
    const float* __restrict__ eb,
    const int* __restrict__ tok_list, const float* __restrict__ score_list,
    const int* __restrict__ cnt, short* __restrict__ part0, short* __restrict__ part1)
{
    const int e = blockIdx.z;
    const int n_e = cnt[e];
    const int xb = blockIdx.x, yb = blockIdx.y;
    const int cb = ((xb >> 2) << 2) + (yb & 3);
    const int rb = (xb & 3) + ((yb >> 2) << 2);
    const int row0 = rb * 256;
    if (row0 >= n_e) return;
    const int col0 = cb * 256;

    __shared__ alignas(16) short lds[2 * 32768];   // 2 x 64 KiB
    __shared__ int   stok[256];
    __shared__ float ssc[256];

    const int tid = threadIdx.x;
    const int lane = tid & 63;
    const int wid = tid >> 6;                 // 0..7
    const int wr = wid >> 2, wc = wid & 3;    // 2M x 4N
    const int fr = lane & 15, fq = lane >> 4;
    const char* ldsb = (const char*)lds;

    if (tid < 256) {
        int slot = row0 + tid;
        if (slot >= n_e) slot = n_e - 1;      // pad rows clamp (stores predicated off)
        stok[tid] = tok_list[e * TT + slot];  // packed: t*2 + slotbit
        ssc[tid]  = score_list[e * TT + slot];
    }
    __syncthreads();

    const int r_ = tid >> 3;                               // 0..63
    const int csw = ((tid & 7) ^ (r_ & 7)) * 8;            // swizzled element offset
    const short* aS[4];
#pragma unroll
    for (int g = 0; g < 4; ++g)
        aS[g] = xbf + (long)(stok[g * 64 + r_] >> 1) * DD + csw;
    const short* bS[4];
#pragma unroll
    for (int g = 0; g < 4; ++g)
        bS[g] = wbf + (long)e * OO * DD + (long)(col0 + g * 64 + r_) * DD + csw;

#define STAGE_A(g, kt) GLD16(aS[g] + (kt) * 64, (char*)lds + ((kt) & 1) * 65536 + ((g) * 512 + tid) * 16)
#define STAGE_B(g, kt) GLD16(bS[g] + (kt) * 64, (char*)lds + ((kt) & 1) * 65536 + 32768 + ((g) * 512 + tid) * 16)

    const int aBase = (wr * 128 + fr) * 128;
    const int bBase = 32768 + (wc * 64 + fr) * 128;
    const int sw0 = (fq ^ (fr & 7)) * 16;
    const int sw1 = ((fq + 4) ^ (fr & 7)) * 16;

    f32x4 acc[8][4];
#pragma unroll
    for (int m = 0; m < 8; ++m)
#pragma unroll
        for (int n = 0; n < 4; ++n) acc[m][n] = f32x4{0.f, 0.f, 0.f, 0.f};

    // prologue: kt0 -> buf0 (kt1 is staged inside kt0's body)
    STAGE_A(0, 0); STAGE_A(1, 0); STAGE_A(2, 0); STAGE_A(3, 0);
    STAGE_B(0, 0); STAGE_B(1, 0); STAGE_B(2, 0); STAGE_B(3, 0);
    asm volatile("s_waitcnt vmcnt(0)");
    BAR();

#pragma unroll 1
    for (int j = 0; j < DD / 64; ++j) {
        const int fb = (j & 1) * 65536;
        const bool st1 = (j + 1) < DD / 64;

        s16x8 a0[4][2], a1[4][2], bb[4][2];

        // reads: A[mh0] (8) + all B (8)
#pragma unroll
        for (int mm = 0; mm < 4; ++mm) {
            a0[mm][0] = *(const s16x8*)(ldsb + fb + aBase + mm * 2048 + sw0);
            a0[mm][1] = *(const s16x8*)(ldsb + fb + aBase + mm * 2048 + sw1);
        }
#pragma unroll
        for (int n = 0; n < 4; ++n) {
            bb[n][0] = *(const s16x8*)(ldsb + fb + bBase + n * 2048 + sw0);
            bb[n][1] = *(const s16x8*)(ldsb + fb + bBase + n * 2048 + sw1);
        }
        // stage ALL 8 half-tiles of kt j+1 into buf^1 (no hazard with buf P)
        if (st1) {
            STAGE_A(0, j + 1); STAGE_A(1, j + 1);
            STAGE_A(2, j + 1); STAGE_A(3, j + 1);
            STAGE_B(0, j + 1); STAGE_B(1, j + 1);
            STAGE_B(2, j + 1); STAGE_B(3, j + 1);
        }
        // MFMA half 1
        __builtin_amdgcn_s_setprio(1);
#pragma unroll
        for (int mm = 0; mm < 4; ++mm)
#pragma unroll
            for (int n = 0; n < 4; ++n) {
                acc[mm][n] = __builtin_amdgcn_mfma_f32_16x16x32_bf16(a0[mm][0], bb[n][0], acc[mm][n], 0, 0, 0);
                acc[mm][n] = __builtin_amdgcn_mfma_f32_16x16x32_bf16(a0[mm][1], bb[n][1], acc[mm][n], 0, 0, 0);
            }
        __builtin_amdgcn_s_setprio(0);
        // reads: A[mh1] (8), then MFMA half 2
#pragma unroll
        for (int mm = 0; mm < 4; ++mm) {
            a1[mm][0] = *(const s16x8*)(ldsb + fb + aBase + 8192 + mm * 2048 + sw0);
            a1[mm][1] = *(const s16x8*)(ldsb + fb + aBase + 8192 + mm * 2048 + sw1);
        }
        __builtin_amdgcn_s_setprio(1);
#pragma unroll
        for (int mm = 0; mm < 4; ++mm)
#pragma unroll
            for (int n = 0; n < 4; ++n) {
                acc[4 + mm][n] = __builtin_amdgcn_mfma_f32_16x16x32_bf16(a1[mm][0], bb[n][0], acc[4 + mm][n], 0, 0, 0);
                acc[4 + mm][n] = __builtin_amdgcn_mfma_f32_16x16x32_bf16(a1[mm][1], bb[n][1], acc[4 + mm][n], 0, 0, 0);
            }
        __builtin_amdgcn_s_setprio(0);

        // end-of-kt: this wave's P-reads retired; Q fully landed; one barrier.
        asm volatile("s_waitcnt lgkmcnt(0)");
        __builtin_amdgcn_sched_barrier(0);
        asm volatile("s_waitcnt vmcnt(0)");
        __builtin_amdgcn_sched_barrier(0);
        BAR();
    }

    // ---- epilogue: bias + score; slot-0 -> part0, slot-1 -> part1 (both bf16)
    float bval[4];
#pragma unroll
    for (int n = 0; n < 4; ++n)
        bval[n] = eb[e * OO + col0 + wc * 64 + n * 16 + fr];

    // C/D layout: col = lane&15, row = (lane>>4)*4 + jj  [m89/m91-verified]
#pragma unroll
    for (int m = 0; m < 8; ++m) {
#pragma unroll
        for (int jj = 0; jj < 4; ++jj) {
            int tslot = wr * 128 + m * 16 + fq * 4 + jj;
            if (row0 + tslot < n_e) {
                int packed = stok[tslot];
                int t = packed >> 1;
                float s = ssc[tslot];
                short* dst = ((packed & 1) == 0) ? part0 : part1;
#pragma unroll
                for (int n = 0; n < 4; ++n) {
                    int o = col0 + wc * 64 + n * 16 + fr;
                    dst[(long)t * OO + o] = f2bf(s * (acc[m][n][jj] + bval[n]));
                }
            }
        }
    }
#undef STAGE_A
#undef STAGE_B
}

extern "C" void kernel_launch(void* const* d_in, const int* in_sizes, int n_in,
                              void* d_out, int out_size, void* d_ws, size_t ws_size,
                              hipStream_t stream) {
    const float* x  = (const float*)d_in[0];
    const float* w1 = (const float*)d_in[1];
    const float* w2 = (const float*)d_in[2];
    const float* ew = (const float*)d_in[3];
    const float* eb = (const float*)d_in[4];
    float* y = (float*)d_out;   // [T*O] then gate_loss at [T*O]

    char* ws = (char*)d_ws;
    short* xbf = (short*)ws;            ws += (size_t)TT * DD * 2;
    short* wbf = (short*)ws;            ws += (size_t)EE * OO * DD * 2;
    short* part0 = (short*)ws;          ws += (size_t)TT * OO * 2;
    short* part1 = (short*)ws;          ws += (size_t)TT * OO * 2;
    int*   tok_list = (int*)ws;         ws += (size_t)EE * TT * 4;
    float* score_list = (float*)ws;     ws += (size_t)EE * TT * 4;
    int*   tk_idx = (int*)ws;           ws += (size_t)TT * 2 * 4;
    float* tk_score = (float*)ws;       ws += (size_t)TT * 2 * 4;
    int*   cnt = (int*)ws;              ws += 64;
    float* imp = (float*)ws;            ws += 64;

    cvt_both_kernel<<<8192, 256, 0, stream>>>(ew, wbf, (long)EE * OO * DD / 8,
                                              x, xbf, (long)TT * DD / 8);
    gate_kernel<<<TT / 4, 256, 0, stream>>>(x, w1, w2, tk_idx, tk_score);
    build_lists<<<EE, 256, 0, stream>>>(tk_idx, tk_score, tok_list, score_list, cnt, imp);
    moe_gemm<<<dim3(8, 32, EE), 512, 0, stream>>>(
        xbf, wbf, eb, tok_list, score_list, cnt, part0, part1);
    combine_kernel<<<2048, 256, 0, stream>>>(y, part0, part1, imp, cnt);
}